// Round 9
// baseline (99.288 us; speedup 1.0000x reference)
//
#include <hip/hip_runtime.h>

// LinearAttention on MI355X (gfx950) — R9.
// R9 vs R8: k2_mega 512 threads / 8 waves (wave = head x px-half), same
// px-tile 64 and LDS (~51KB) -> 3 blocks/CU = 6 waves/SIMD (was ~2).
// Per-wave state halved (acc 2x2, W frags loaded in-loop); PV K-split per
// px-half + LDS pair-combine; sumep 128 slots/batch-ch (2 per px-tile).
// Workspace:
//   W16   fp16[384*256]  @ 0         (pre-scaled by g_norm*16)
//   Wo16  fp16[256*128]  @ 196608
//   qhat  fp16[16][4096][128] @ 262144
//   ctx   f32 [16][4096] @ 17039360
//   sume  f32 [16][128]  @ 17301504
//   M     fp16[16][256][128] @ 17309696
//   ctxp  f32 [16][64][4][32][32] @ 18358272
//   sumep f32 [16][128][128] @ 35135488  (ends 36184064)

typedef _Float16 half8 __attribute__((ext_vector_type(8)));
typedef _Float16 half4 __attribute__((ext_vector_type(4)));
typedef float f32x4 __attribute__((ext_vector_type(4)));

#define SCALE_F 0.17677669529663687f

// ---------------- kW: convert weights. W16 = W_qkv * g_norm*16 (per col). ---
__global__ __launch_bounds__(256) void kW(const float* __restrict__ W_qkv,
                                          const float* __restrict__ W_out,
                                          const float* __restrict__ g_norm,
                                          _Float16* __restrict__ W16,
                                          _Float16* __restrict__ Wo16) {
  const int t = threadIdx.x;
  __shared__ float g16s[256];
  g16s[t] = g_norm[t] * 16.0f;
  __syncthreads();
  #pragma unroll
  for (int i = 0; i < 8; ++i) {
    int idx = blockIdx.x * 2048 + i * 256 + t;   // 32768 f32x4 chunks total
    if (idx < 24576) {
      f32x4 v = *(const f32x4*)(W_qkv + (size_t)idx * 4);
      int c0 = (idx & 63) * 4;
      half4 h = {(_Float16)(v[0] * g16s[c0]), (_Float16)(v[1] * g16s[c0 + 1]),
                 (_Float16)(v[2] * g16s[c0 + 2]), (_Float16)(v[3] * g16s[c0 + 3])};
      *(half4*)(W16 + (size_t)idx * 4) = h;
    } else {
      f32x4 v = *(const f32x4*)(W_out + (size_t)(idx - 24576) * 4);
      half4 h = {(_Float16)v[0], (_Float16)v[1], (_Float16)v[2], (_Float16)v[3]};
      *(half4*)(Wo16 + (size_t)(idx - 24576) * 4) = h;
    }
  }
}

// ---------------- k2_mega (R9): 512 thr, wave = (head, px-half) ----------
__global__ __launch_bounds__(512, 6) void k2_mega(const _Float16* __restrict__ W16,
                                                  const float* __restrict__ x,
                                                  _Float16* __restrict__ qhat,
                                                  float* __restrict__ ctxp,
                                                  float* __restrict__ sumep) {
  const int pt = blockIdx.x, b = blockIdx.y;
  const int p0 = pt * 64;
  const int t = threadIdx.x;
  const int w = t >> 6, l = t & 63;
  const int h = w >> 1, ph = w & 1;
  const int lg = l >> 4, ll = l & 15;
  __shared__ __align__(1024) char smem[51456];
  char* xbuf = smem;            // [64 px][512 B] fp16, chunk c at
                                // c ^ (px&15) ^ (((px>>4)&1)<<4)
  char* r2 = smem + 32768;      // 16 KB: qt (mt0) / wt (mt1..2)
  char* vt = smem;              // overlays xbuf[0,16K) after mt2 GEMM
  float* scr = (float*)(smem + 16384);    // overlays xbuf[16K,32K) for PV combine
  float* psum = (float*)(smem + 49152);   // [64][8]
  float* sinvp = (float*)(smem + 51200);  // [64]

  // ---- stage raw x: thread owns px=l, 32 ch (wave slice); rms in-register --
  {
    const float* xb = x + ((size_t)(b * 256 + w * 32)) * 4096 + p0 + l;
    float rsum = 0.f;
    #pragma unroll
    for (int it = 0; it < 8; ++it) {
      const float* xc = xb + (size_t)it * 4 * 4096;
      float v0 = xc[0];
      float v1 = xc[4096];
      float v2 = xc[8192];
      float v3 = xc[12288];
      half4 hv = {(_Float16)v0, (_Float16)v1, (_Float16)v2, (_Float16)v3};
      #pragma unroll
      for (int j = 0; j < 4; ++j) { float f = (float)hv[j]; rsum += f * f; }
      int c = w * 4 + (it >> 1);
      int swz = c ^ (l & 15) ^ (((l >> 4) & 1) << 4);
      *(half4*)(xbuf + l * 512 + (swz << 4) + (it & 1) * 8) = hv;
    }
    psum[l * 8 + w] = rsum;
  }
  __syncthreads();
  if (t < 64) {
    float s = 1e-12f;
    #pragma unroll
    for (int j = 0; j < 8; ++j) s += psum[t * 8 + j];
    sinvp[t] = rsqrtf(s);
  }
  __syncthreads();
  float sv[2];
  #pragma unroll
  for (int nf = 0; nf < 2; ++nf) sv[nf] = sinvp[(ph * 2 + nf) * 16 + ll];

  const f32x4 fz = {0.f, 0.f, 0.f, 0.f};
  _Float16* qb = qhat + ((size_t)b * 4096 + p0) * 128;
  #pragma unroll
  for (int mt = 0; mt < 3; ++mt) {
    f32x4 acc[2][2];
    #pragma unroll
    for (int i = 0; i < 2; ++i)
      #pragma unroll
      for (int j = 0; j < 2; ++j) acc[i][j] = fz;
    const _Float16* Wmt = W16 + (size_t)(mt * 128 + h * 32) * 256;
    #pragma unroll
    for (int ks = 0; ks < 8; ++ks) {
      half8 af[2], bf[2];
      #pragma unroll
      for (int mf = 0; mf < 2; ++mf)
        af[mf] = *(const half8*)(Wmt + (size_t)(mf * 16 + ll) * 256 + ks * 32 + lg * 8);
      #pragma unroll
      for (int nf = 0; nf < 2; ++nf) {
        int nfg = ph * 2 + nf;
        bf[nf] = *(const half8*)(xbuf + (nfg * 16 + ll) * 512 +
                                 ((((ks * 4 + lg) ^ ll) ^ ((nfg & 1) << 4)) << 4));
      }
      #pragma unroll
      for (int mf = 0; mf < 2; ++mf)
        #pragma unroll
        for (int nf = 0; nf < 2; ++nf)
          acc[mf][nf] = __builtin_amdgcn_mfma_f32_16x16x32_f16(af[mf], bf[nf], acc[mf][nf], 0, 0, 0);
    }
    // acc at (ch-in-head = mf*16+lg*4+rr, px = (ph*2+nf)*16+ll); logit = acc*sv
    if (mt == 0) {
      // q-softmax over head's 32 ch (in-register; reduce over lg via shfl)
      float s[2] = {0.f, 0.f};
      #pragma unroll
      for (int mf = 0; mf < 2; ++mf)
        #pragma unroll
        for (int nf = 0; nf < 2; ++nf)
          #pragma unroll
          for (int rr = 0; rr < 4; ++rr) {
            float v = __expf(acc[mf][nf][rr] * sv[nf]);
            acc[mf][nf][rr] = v;
            s[nf] += v;
          }
      #pragma unroll
      for (int nf = 0; nf < 2; ++nf) {
        s[nf] += __shfl_xor(s[nf], 16);
        s[nf] += __shfl_xor(s[nf], 32);
        s[nf] = 1.0f / s[nf];
      }
      #pragma unroll
      for (int mf = 0; mf < 2; ++mf)
        #pragma unroll
        for (int nf = 0; nf < 2; ++nf) {
          int px = (ph * 2 + nf) * 16 + ll;
          int cphys = (h * 4 + mf * 2 + (lg >> 1)) ^ (px & 15);
          half4 hv;
          #pragma unroll
          for (int rr = 0; rr < 4; ++rr) hv[rr] = (_Float16)(acc[mf][nf][rr] * s[nf]);
          *(half4*)(r2 + px * 256 + (cphys << 4) + (lg & 1) * 8) = hv;
        }
      __syncthreads();
      #pragma unroll
      for (int i = 0; i < 2; ++i) {        // coalesced qhat store (1024 half8)
        int q = i * 512 + t;
        int px = q >> 4, g = q & 15;
        half8 hv = *(const half8*)(r2 + px * 256 + ((g ^ (px & 15)) << 4));
        *(half8*)(qb + (size_t)px * 128 + g * 8) = hv;
      }
      __syncthreads();                     // qt reads done before wt reuse
    } else if (mt == 1) {
      // k: e = exp(sv*logit - 10); rowsum partial (this px-half); -> wt
      float rs[2][4];
      #pragma unroll
      for (int mf = 0; mf < 2; ++mf)
        #pragma unroll
        for (int rr = 0; rr < 4; ++rr) rs[mf][rr] = 0.f;
      #pragma unroll
      for (int mf = 0; mf < 2; ++mf)
        #pragma unroll
        for (int nf = 0; nf < 2; ++nf)
          #pragma unroll
          for (int rr = 0; rr < 4; ++rr) {
            float v = __expf(acc[mf][nf][rr] * sv[nf] - 10.f);
            acc[mf][nf][rr] = v;
            rs[mf][rr] += v;
          }
      #pragma unroll
      for (int mf = 0; mf < 2; ++mf)
        #pragma unroll
        for (int rr = 0; rr < 4; ++rr) {
          float v = rs[mf][rr];
          v += __shfl_xor(v, 1);
          v += __shfl_xor(v, 2);
          v += __shfl_xor(v, 4);
          v += __shfl_xor(v, 8);
          rs[mf][rr] = v;
        }
      if (ll == 0) {
        #pragma unroll
        for (int mf = 0; mf < 2; ++mf)
          #pragma unroll
          for (int rr = 0; rr < 4; ++rr)
            sumep[((size_t)b * 128 + h * 32 + mf * 16 + lg * 4 + rr) * 128 + pt * 2 + ph] =
                rs[mf][rr];
      }
      #pragma unroll
      for (int mf = 0; mf < 2; ++mf)
        #pragma unroll
        for (int nf = 0; nf < 2; ++nf)
          #pragma unroll
          for (int rr = 0; rr < 4; ++rr) {
            int ch = h * 32 + mf * 16 + lg * 4 + rr;
            int px = (ph * 2 + nf) * 16 + ll;
            *(_Float16*)(r2 + ch * 128 + (((px >> 3) ^ (ch & 7)) << 4) + (px & 7) * 2) =
                (_Float16)acc[mf][nf][rr];
          }
      // no barrier: wt cells read in PV only by the wave that wrote them
    } else {
      __syncthreads();                     // all xbuf reads done before vt/scr overlay
      #pragma unroll
      for (int mf = 0; mf < 2; ++mf)
        #pragma unroll
        for (int nf = 0; nf < 2; ++nf)
          #pragma unroll
          for (int rr = 0; rr < 4; ++rr) {
            int ch = h * 32 + mf * 16 + lg * 4 + rr;
            int px = (ph * 2 + nf) * 16 + ll;
            *(_Float16*)(vt + ch * 128 + (((px >> 3) ^ (ch & 7)) << 4) + (px & 7) * 2) =
                (_Float16)(acc[mf][nf][rr] * sv[nf]);
          }
      // PV over this wave's px-half (K=32): ctx_h[d][e] partial
      f32x4 ca[2][2] = {{fz, fz}, {fz, fz}};
      {
        half8 a2[2], b2[2];
        int c = ph * 4 + lg;
        #pragma unroll
        for (int ti = 0; ti < 2; ++ti) {
          int ra = h * 32 + ti * 16 + ll;
          int cc = (c ^ (ra & 7)) << 4;
          a2[ti] = *(const half8*)(r2 + ra * 128 + cc);
          b2[ti] = *(const half8*)(vt + ra * 128 + cc);
        }
        #pragma unroll
        for (int ti = 0; ti < 2; ++ti)
          #pragma unroll
          for (int tj = 0; tj < 2; ++tj)
            ca[ti][tj] = __builtin_amdgcn_mfma_f32_16x16x32_f16(a2[ti], b2[tj], ca[ti][tj], 0, 0, 0);
      }
      if (ph == 1) {
        #pragma unroll
        for (int ti = 0; ti < 2; ++ti)
          #pragma unroll
          for (int tj = 0; tj < 2; ++tj)
            #pragma unroll
            for (int rr = 0; rr < 4; ++rr)
              scr[h * 1024 + (ti * 16 + lg * 4 + rr) * 32 + tj * 16 + ll] = ca[ti][tj][rr];
      }
      __syncthreads();
      if (ph == 0) {
        float* cp = ctxp + (size_t)(((b * 64 + pt) * 4) + h) * 1024;
        #pragma unroll
        for (int ti = 0; ti < 2; ++ti)
          #pragma unroll
          for (int tj = 0; tj < 2; ++tj)
            #pragma unroll
            for (int rr = 0; rr < 4; ++rr) {
              int o = (ti * 16 + lg * 4 + rr) * 32 + tj * 16 + ll;
              cp[o] = ca[ti][tj][rr] + scr[h * 1024 + o];
            }
      }
    }
  }
}

// ---------------- k3_reduce: fold ctxp/sumep partials -> ctx, sume ----------
__global__ __launch_bounds__(256) void k3_reduce(const float* __restrict__ ctxp,
                                                 const float* __restrict__ sumep,
                                                 float* __restrict__ ctx,
                                                 float* __restrict__ sume) {
  const int sl = blockIdx.x, b = blockIdx.y;
  const int t = threadIdx.x;
  if (sl == 0 && t < 128) {
    float s = 0.f;
    const float* sp = sumep + ((size_t)b * 128 + t) * 128;
    #pragma unroll 8
    for (int pt = 0; pt < 128; ++pt) s += sp[pt];
    sume[b * 128 + t] = s;
  }
  float a = 0.f;
  const float* p = ctxp + (size_t)b * 64 * 4096 + sl * 256 + t;
  #pragma unroll 8
  for (int pt = 0; pt < 64; ++pt) a += p[(size_t)pt * 4096];
  ctx[(size_t)b * 4096 + sl * 256 + t] = a;
}

// ---------------- k4b: M_h = W_out16[:,h*32..] @ (ctx^T * SCALE/sume), MFMA.
__global__ __launch_bounds__(256) void k4b_fold(const _Float16* __restrict__ Wo16,
                                                const float* __restrict__ ctx,
                                                const float* __restrict__ sumexp,
                                                _Float16* __restrict__ M) {
  const int mq = blockIdx.x, b = blockIdx.y;
  const int t = threadIdx.x;
  const int h = t >> 6, l = t & 63;
  const int m0 = mq * 64;
  const float* cb = ctx + (size_t)(b * 4 + h) * 1024;
  const float* sb = sumexp + b * 128 + h * 32;
  half8 bf[2];
  #pragma unroll
  for (int n0 = 0; n0 < 2; ++n0) {
    int d = n0 * 16 + (l & 15);
    float s = SCALE_F / sb[d];
    const float* ce = cb + d * 32 + (l >> 4) * 8;
    half8 hb;
    #pragma unroll
    for (int j = 0; j < 8; ++j) hb[j] = (_Float16)(ce[j] * s);
    bf[n0] = hb;
  }
  const f32x4 fz = {0.f, 0.f, 0.f, 0.f};
  _Float16* Mb = M + (size_t)(b * 256) * 128;
  #pragma unroll
  for (int mf = 0; mf < 4; ++mf) {
    int row = m0 + mf * 16 + (l & 15);
    half8 af = *(const half8*)(Wo16 + (size_t)row * 128 + h * 32 + (l >> 4) * 8);
    #pragma unroll
    for (int n0 = 0; n0 < 2; ++n0) {
      f32x4 c = __builtin_amdgcn_mfma_f32_16x16x32_f16(af, bf[n0], fz, 0, 0, 0);
      #pragma unroll
      for (int rr = 0; rr < 4; ++rr) {
        int r = m0 + mf * 16 + (l >> 4) * 4 + rr;
        Mb[(size_t)r * 128 + h * 32 + n0 * 16 + (l & 15)] = (_Float16)c[rr];
      }
    }
  }
}

// ---------------- k5: out = rmsnorm(M @ qhat + b_out, g_out), f32 ----------
__global__ __launch_bounds__(256) void k5c_out(const _Float16* __restrict__ M,
                                               const _Float16* __restrict__ qhat,
                                               const float* __restrict__ b_out,
                                               const float* __restrict__ g_out,
                                               float* __restrict__ out) {
  const int pt = blockIdx.x, b = blockIdx.y;
  const int p0 = pt * 64;
  const int t = threadIdx.x;
  const int wid = t >> 6, l = t & 63;
  __shared__ __align__(16) char smem[81920];
  float* rp = (float*)smem;                   // [256][68]
  float* bo = (float*)(smem + 69632);
  float* g16o = (float*)(smem + 70656);
  float* psum = (float*)(smem + 71680);
  float* sinvp = (float*)(smem + 72704);
  const _Float16* Mb = M + (size_t)b * 256 * 128;
  const _Float16* Qb = qhat + ((size_t)b * 4096 + p0) * 128;
  #pragma unroll
  for (int i = 0; i < 16; ++i) {
    int ci = t + 256 * i;
    int r = ci >> 4, c = ci & 15;
    *(half8*)(smem + r * 256 + ((c ^ (r & 15)) << 4)) = *(const half8*)(Mb + (size_t)r * 128 + c * 8);
  }
  #pragma unroll
  for (int i = 0; i < 4; ++i) {
    int ci = t + 256 * i;
    int r = ci >> 4, c = ci & 15;
    *(half8*)(smem + 65536 + r * 256 + ((c ^ (r & 15)) << 4)) = *(const half8*)(Qb + (size_t)r * 128 + c * 8);
  }
  __syncthreads();
  const f32x4 fz = {0.f, 0.f, 0.f, 0.f};
  f32x4 acc[4][4];
  #pragma unroll
  for (int i = 0; i < 4; ++i)
    #pragma unroll
    for (int j = 0; j < 4; ++j) acc[i][j] = fz;
  #pragma unroll
  for (int kk = 0; kk < 4; ++kk) {
    half8 af[4], bf[4];
    int ck = kk * 4 + (l >> 4);
    #pragma unroll
    for (int mf = 0; mf < 4; ++mf) {
      int r = wid * 64 + mf * 16 + (l & 15);
      af[mf] = *(const half8*)(smem + r * 256 + ((ck ^ (r & 15)) << 4));
    }
    #pragma unroll
    for (int nf = 0; nf < 4; ++nf) {
      int r = nf * 16 + (l & 15);
      bf[nf] = *(const half8*)(smem + 65536 + r * 256 + ((ck ^ (r & 15)) << 4));
    }
    #pragma unroll
    for (int mf = 0; mf < 4; ++mf)
      #pragma unroll
      for (int nf = 0; nf < 4; ++nf)
        acc[mf][nf] = __builtin_amdgcn_mfma_f32_16x16x32_f16(af[mf], bf[nf], acc[mf][nf], 0, 0, 0);
  }
  __syncthreads();
  bo[t] = b_out[t];
  g16o[t] = g_out[t] * 16.0f;
  #pragma unroll
  for (int mf = 0; mf < 4; ++mf)
    #pragma unroll
    for (int nf = 0; nf < 4; ++nf)
      #pragma unroll
      for (int rr = 0; rr < 4; ++rr) {
        int r = wid * 64 + mf * 16 + (l >> 4) * 4 + rr;
        int px = nf * 16 + (l & 15);
        rp[r * 68 + px] = acc[mf][nf][rr];
      }
  __syncthreads();
  {
    int px = t & 63, q = t >> 6;
    float s = 0.f;
    #pragma unroll
    for (int i = 0; i < 64; ++i) {
      int r = q * 64 + i;
      float f = rp[r * 68 + px] + bo[r];
      s += f * f;
    }
    psum[px * 4 + q] = s;
  }
  __syncthreads();
  if (t < 64)
    sinvp[t] = rsqrtf(psum[t * 4] + psum[t * 4 + 1] + psum[t * 4 + 2] + psum[t * 4 + 3] + 1e-12f);
  __syncthreads();
  float* ob = out + (size_t)(b * 256) * 4096 + p0;
  #pragma unroll
  for (int i = 0; i < 16; ++i) {
    int idx4 = t + 256 * i;
    int r = idx4 >> 4, px4 = (idx4 & 15) * 4;
    f32x4 v;
    #pragma unroll
    for (int ii = 0; ii < 4; ++ii)
      v[ii] = (rp[r * 68 + px4 + ii] + bo[r]) * sinvp[px4 + ii] * g16o[r];
    *(f32x4*)(ob + (size_t)r * 4096 + px4) = v;
  }
}

extern "C" void kernel_launch(void* const* d_in, const int* in_sizes, int n_in,
                              void* d_out, int out_size, void* d_ws, size_t ws_size,
                              hipStream_t stream) {
  const float* x      = (const float*)d_in[0];
  const float* W_qkv  = (const float*)d_in[1];
  const float* W_out  = (const float*)d_in[2];
  const float* b_out  = (const float*)d_in[3];
  const float* g_norm = (const float*)d_in[4];
  const float* g_out  = (const float*)d_in[5];
  float* out = (float*)d_out;
  char* ws = (char*)d_ws;
  if (ws_size < 36184064) return;

  _Float16* W16   = (_Float16*)(ws);
  _Float16* Wo16  = (_Float16*)(ws + 196608);
  _Float16* qhat  = (_Float16*)(ws + 262144);
  float*    ctx   = (float*)(ws + 17039360);
  float*    sume  = (float*)(ws + 17301504);
  _Float16* M     = (_Float16*)(ws + 17309696);
  float*    ctxp  = (float*)(ws + 18358272);
  float*    sumep = (float*)(ws + 35135488);

  kW<<<16, 256, 0, stream>>>(W_qkv, W_out, g_norm, W16, Wo16);
  k2_mega<<<dim3(64, 16), 512, 0, stream>>>(W16, x, qhat, ctxp, sumep);
  k3_reduce<<<dim3(16, 16), 256, 0, stream>>>(ctxp, sumep, ctx, sume);
  k4b_fold<<<dim3(4, 16), 256, 0, stream>>>(Wo16, ctx, sume, M);
  k5c_out<<<dim3(64, 16), 256, 0, stream>>>(M, qhat, b_out, g_out, out);
}

// Round 11
// 77.857 us; speedup vs baseline: 1.2753x; 1.2753x over previous
//
#include <hip/hip_runtime.h>

// LinearAttention on MI355X (gfx950) — R11.
// R11 vs R10: fixed UB in the 4x4 shfl transpose — shfls are now executed
// UNCONDITIONALLY in uniform control flow (pre-select payload, shfl, post-
// select). R10's divergent-ternary shfl read inactive lanes -> garbage.
// Everything else identical to R10 (16B/lane staging, W afA/afB double
// buffer with prefetch under epilogues, launch_bounds(256,3)).
// Workspace:
//   W16   fp16[384*256]  @ 0         (pre-scaled by g_norm*16)
//   Wo16  fp16[256*128]  @ 196608
//   qhat  fp16[16][4096][128] @ 262144
//   ctx   f32 [16][4096] @ 17039360
//   sume  f32 [16][128]  @ 17301504
//   M     fp16[16][256][128] @ 17309696
//   ctxp  f32 [16][64][4][32][32] @ 18358272
//   sumep f32 [16][128][64]  @ 35135488  (ends 35659776)

typedef _Float16 half8 __attribute__((ext_vector_type(8)));
typedef _Float16 half4 __attribute__((ext_vector_type(4)));
typedef float f32x4 __attribute__((ext_vector_type(4)));

#define SCALE_F 0.17677669529663687f

// ---------------- kW: convert weights. W16 = W_qkv * g_norm*16 (per col). ---
__global__ __launch_bounds__(256) void kW(const float* __restrict__ W_qkv,
                                          const float* __restrict__ W_out,
                                          const float* __restrict__ g_norm,
                                          _Float16* __restrict__ W16,
                                          _Float16* __restrict__ Wo16) {
  const int t = threadIdx.x;
  __shared__ float g16s[256];
  g16s[t] = g_norm[t] * 16.0f;
  __syncthreads();
  #pragma unroll
  for (int i = 0; i < 8; ++i) {
    int idx = blockIdx.x * 2048 + i * 256 + t;   // 32768 f32x4 chunks total
    if (idx < 24576) {
      f32x4 v = *(const f32x4*)(W_qkv + (size_t)idx * 4);
      int c0 = (idx & 63) * 4;
      half4 h = {(_Float16)(v[0] * g16s[c0]), (_Float16)(v[1] * g16s[c0 + 1]),
                 (_Float16)(v[2] * g16s[c0 + 2]), (_Float16)(v[3] * g16s[c0 + 3])};
      *(half4*)(W16 + (size_t)idx * 4) = h;
    } else {
      f32x4 v = *(const f32x4*)(W_out + (size_t)(idx - 24576) * 4);
      half4 h = {(_Float16)v[0], (_Float16)v[1], (_Float16)v[2], (_Float16)v[3]};
      *(half4*)(Wo16 + (size_t)(idx - 24576) * 4) = h;
    }
  }
}

#define LOAD_AF(dst, mtv)                                                            \
  {                                                                                  \
    const _Float16* Wm_ = W16 + (size_t)((mtv) * 128 + h * 32) * 256;                \
    _Pragma("unroll")                                                                \
    for (int ks = 0; ks < 8; ++ks)                                                   \
      _Pragma("unroll")                                                              \
      for (int mf = 0; mf < 2; ++mf)                                                 \
        dst[ks][mf] = *(const half8*)(Wm_ + (size_t)(mf * 16 + ll) * 256 +           \
                                      ks * 32 + lg * 8);                             \
  }

#define GEMM_PHASE(afc)                                                              \
  {                                                                                  \
    _Pragma("unroll")                                                                \
    for (int i = 0; i < 2; ++i)                                                      \
      _Pragma("unroll")                                                              \
      for (int j = 0; j < 4; ++j) acc[i][j] = fz;                                    \
    _Pragma("unroll")                                                                \
    for (int ks = 0; ks < 8; ++ks) {                                                 \
      half8 bf[4];                                                                   \
      _Pragma("unroll")                                                              \
      for (int nf = 0; nf < 4; ++nf)                                                 \
        bf[nf] = *(const half8*)(xbuf + (nf * 16 + ll) * 512 +                       \
                                 ((((ks * 4 + lg) ^ ll) ^ ((nf & 1) << 4)) << 4));   \
      _Pragma("unroll")                                                              \
      for (int mf = 0; mf < 2; ++mf)                                                 \
        _Pragma("unroll")                                                            \
        for (int nf = 0; nf < 4; ++nf)                                               \
          acc[mf][nf] =                                                              \
              __builtin_amdgcn_mfma_f32_16x16x32_f16(afc[ks][mf], bf[nf],            \
                                                     acc[mf][nf], 0, 0, 0);          \
    }                                                                                \
  }

// ---------------- k2_mega (R11): 256 thr, wave=head, shfl-transpose staging --
__global__ __launch_bounds__(256, 3) void k2_mega(const _Float16* __restrict__ W16,
                                                  const float* __restrict__ x,
                                                  _Float16* __restrict__ qhat,
                                                  float* __restrict__ ctxp,
                                                  float* __restrict__ sumep) {
  const int pt = blockIdx.x, b = blockIdx.y;
  const int p0 = pt * 64;
  const int t = threadIdx.x;
  const int h = t >> 6, l = t & 63;
  const int lg = l >> 4, ll = l & 15;
  const int u = l & 3;
  __shared__ __align__(1024) char smem[50432];
  char* xbuf = smem;            // [64 px][512 B] fp16, chunk c at
                                // c ^ (px&15) ^ (((px>>4)&1)<<4)
  char* r2 = smem + 32768;      // 16 KB: qt (mt0) / wt (mt1..2)
  char* vt = smem;              // overlays xbuf after mt2 GEMM
  float* psum = (float*)(smem + 49152);   // [64][4]
  float* sinvp = (float*)(smem + 50176);  // [64]

  // ---- issue all x loads (16B/lane): lane quad = 4 consecutive ch, 4 px ----
  f32x4 vx[16];
  const float* xb = x + ((size_t)(b * 256 + h * 64)) * 4096 + p0 + (l & ~3);
  #pragma unroll
  for (int it = 0; it < 16; ++it)
    vx[it] = *(const f32x4*)(xb + (size_t)(it * 4 + u) * 4096);
  // ---- W fragments for mt=0 (L2-hot, overlaps with x loads) ----
  half8 afA[8][2], afB[8][2];
  LOAD_AF(afA, 0);
  // ---- 4x4 transpose per iter: pre-select payload -> UNCONDITIONAL shfl ->
  //      post-select (uniform control flow, no divergent-shfl UB) ----
  float rsum = 0.f;
  #pragma unroll
  for (int it = 0; it < 16; ++it) {
    f32x4 v = vx[it];
    // stage 1: xor 1
    float sA = __shfl_xor((u & 1) ? v[0] : v[1], 1);
    float sB = __shfl_xor((u & 1) ? v[2] : v[3], 1);
    float a0 = (u & 1) ? sA : v[0];
    float a1 = (u & 1) ? v[1] : sA;
    float a2 = (u & 1) ? sB : v[2];
    float a3 = (u & 1) ? v[3] : sB;
    // stage 2: xor 2
    float sC = __shfl_xor((u & 2) ? a0 : a2, 2);
    float sD = __shfl_xor((u & 2) ? a1 : a3, 2);
    float w0 = (u & 2) ? sC : a0;
    float w1 = (u & 2) ? sD : a1;
    float w2 = (u & 2) ? a2 : sC;
    float w3 = (u & 2) ? a3 : sD;
    half4 hv = {(_Float16)w0, (_Float16)w1, (_Float16)w2, (_Float16)w3};
    #pragma unroll
    for (int j = 0; j < 4; ++j) { float f = (float)hv[j]; rsum += f * f; }
    int c = h * 8 + (it >> 1);
    int swz = c ^ (l & 15) ^ (((l >> 4) & 1) << 4);
    *(half4*)(xbuf + l * 512 + (swz << 4) + (it & 1) * 8) = hv;
  }
  psum[l * 4 + h] = rsum;
  __syncthreads();
  if (t < 64)
    sinvp[t] = rsqrtf(psum[t * 4] + psum[t * 4 + 1] + psum[t * 4 + 2] + psum[t * 4 + 3] + 1e-12f);
  __syncthreads();
  float sv[4];
  #pragma unroll
  for (int nf = 0; nf < 4; ++nf) sv[nf] = sinvp[nf * 16 + ll];

  const f32x4 fz = {0.f, 0.f, 0.f, 0.f};
  f32x4 acc[2][4];

  // ================= mt = 0 : q =================
  GEMM_PHASE(afA);
  LOAD_AF(afB, 1);                       // prefetch W(k) under q-epilogue
  {
    float s[4] = {0.f, 0.f, 0.f, 0.f};
    #pragma unroll
    for (int mf = 0; mf < 2; ++mf)
      #pragma unroll
      for (int nf = 0; nf < 4; ++nf)
        #pragma unroll
        for (int rr = 0; rr < 4; ++rr) {
          float v = __expf(acc[mf][nf][rr] * sv[nf]);
          acc[mf][nf][rr] = v;
          s[nf] += v;
        }
    #pragma unroll
    for (int nf = 0; nf < 4; ++nf) {
      s[nf] += __shfl_xor(s[nf], 16);
      s[nf] += __shfl_xor(s[nf], 32);
      s[nf] = 1.0f / s[nf];
    }
    #pragma unroll
    for (int mf = 0; mf < 2; ++mf)
      #pragma unroll
      for (int nf = 0; nf < 4; ++nf) {
        int px = nf * 16 + ll;
        int cphys = (h * 4 + mf * 2 + (lg >> 1)) ^ (px & 15);
        half4 hv;
        #pragma unroll
        for (int rr = 0; rr < 4; ++rr) hv[rr] = (_Float16)(acc[mf][nf][rr] * s[nf]);
        *(half4*)(r2 + px * 256 + (cphys << 4) + (lg & 1) * 8) = hv;
      }
    __syncthreads();
    _Float16* qb = qhat + ((size_t)b * 4096 + p0) * 128;
    #pragma unroll
    for (int i = 0; i < 4; ++i) {        // coalesced qhat store
      int q = i * 256 + t;
      int px = q >> 4, g = q & 15;
      half8 hv = *(const half8*)(r2 + px * 256 + ((g ^ (px & 15)) << 4));
      *(half8*)(qb + (size_t)px * 128 + g * 8) = hv;
    }
    __syncthreads();                     // qt reads done before wt reuse
  }

  // ================= mt = 1 : k =================
  GEMM_PHASE(afB);
  LOAD_AF(afA, 2);                       // prefetch W(v) under k-epilogue
  {
    float rs[2][4];
    #pragma unroll
    for (int mf = 0; mf < 2; ++mf)
      #pragma unroll
      for (int rr = 0; rr < 4; ++rr) rs[mf][rr] = 0.f;
    #pragma unroll
    for (int mf = 0; mf < 2; ++mf)
      #pragma unroll
      for (int nf = 0; nf < 4; ++nf)
        #pragma unroll
        for (int rr = 0; rr < 4; ++rr) {
          float v = __expf(acc[mf][nf][rr] * sv[nf] - 10.f);
          acc[mf][nf][rr] = v;
          rs[mf][rr] += v;
        }
    #pragma unroll
    for (int mf = 0; mf < 2; ++mf)
      #pragma unroll
      for (int rr = 0; rr < 4; ++rr) {
        float v = rs[mf][rr];
        v += __shfl_xor(v, 1);
        v += __shfl_xor(v, 2);
        v += __shfl_xor(v, 4);
        v += __shfl_xor(v, 8);
        rs[mf][rr] = v;
      }
    if (ll == 0) {
      #pragma unroll
      for (int mf = 0; mf < 2; ++mf)
        #pragma unroll
        for (int rr = 0; rr < 4; ++rr)
          sumep[((size_t)b * 128 + h * 32 + mf * 16 + lg * 4 + rr) * 64 + pt] = rs[mf][rr];
    }
    #pragma unroll
    for (int mf = 0; mf < 2; ++mf)
      #pragma unroll
      for (int nf = 0; nf < 4; ++nf)
        #pragma unroll
        for (int rr = 0; rr < 4; ++rr) {
          int ch = h * 32 + mf * 16 + lg * 4 + rr;
          int px = nf * 16 + ll;
          *(_Float16*)(r2 + ch * 128 + (((px >> 3) ^ (ch & 7)) << 4) + (px & 7) * 2) =
              (_Float16)acc[mf][nf][rr];
        }
    // no barrier: wt rows read in PV only by the wave that wrote them
  }

  // ================= mt = 2 : v + PV =================
  GEMM_PHASE(afA);
  {
    __syncthreads();                     // all xbuf reads done before vt overlay
    #pragma unroll
    for (int mf = 0; mf < 2; ++mf)
      #pragma unroll
      for (int nf = 0; nf < 4; ++nf)
        #pragma unroll
        for (int rr = 0; rr < 4; ++rr) {
          int ch = h * 32 + mf * 16 + lg * 4 + rr;
          int px = nf * 16 + ll;
          *(_Float16*)(vt + ch * 128 + (((px >> 3) ^ (ch & 7)) << 4) + (px & 7) * 2) =
              (_Float16)(acc[mf][nf][rr] * sv[nf]);
        }
    // PV: ctx_h[d][e] = sum_px w[d,px] v[e,px], K=64
    f32x4 ca[2][2] = {{fz, fz}, {fz, fz}};
    #pragma unroll
    for (int ks2 = 0; ks2 < 2; ++ks2) {
      half8 a2[2], b2[2];
      #pragma unroll
      for (int ti = 0; ti < 2; ++ti) {
        int ra = h * 32 + ti * 16 + ll;
        int cc = (ks2 * 4 + lg) ^ (ra & 7);
        a2[ti] = *(const half8*)(r2 + ra * 128 + (cc << 4));
        b2[ti] = *(const half8*)(vt + ra * 128 + (cc << 4));
      }
      #pragma unroll
      for (int ti = 0; ti < 2; ++ti)
        #pragma unroll
        for (int tj = 0; tj < 2; ++tj)
          ca[ti][tj] = __builtin_amdgcn_mfma_f32_16x16x32_f16(a2[ti], b2[tj], ca[ti][tj], 0, 0, 0);
    }
    float* cp = ctxp + (size_t)(((b * 64 + pt) * 4) + h) * 1024;
    #pragma unroll
    for (int ti = 0; ti < 2; ++ti)
      #pragma unroll
      for (int tj = 0; tj < 2; ++tj)
        #pragma unroll
        for (int rr = 0; rr < 4; ++rr)
          cp[(ti * 16 + lg * 4 + rr) * 32 + tj * 16 + ll] = ca[ti][tj][rr];
  }
}

// ---------------- k3_reduce: fold ctxp/sumep partials -> ctx, sume ----------
__global__ __launch_bounds__(256) void k3_reduce(const float* __restrict__ ctxp,
                                                 const float* __restrict__ sumep,
                                                 float* __restrict__ ctx,
                                                 float* __restrict__ sume) {
  const int sl = blockIdx.x, b = blockIdx.y;
  const int t = threadIdx.x;
  if (sl == 0 && t < 128) {
    float s = 0.f;
    const float* sp = sumep + ((size_t)b * 128 + t) * 64;
    #pragma unroll 8
    for (int pt = 0; pt < 64; ++pt) s += sp[pt];
    sume[b * 128 + t] = s;
  }
  float a = 0.f;
  const float* p = ctxp + (size_t)b * 64 * 4096 + sl * 256 + t;
  #pragma unroll 8
  for (int pt = 0; pt < 64; ++pt) a += p[(size_t)pt * 4096];
  ctx[(size_t)b * 4096 + sl * 256 + t] = a;
}

// ---------------- k4b: M_h = W_out16[:,h*32..] @ (ctx^T * SCALE/sume), MFMA.
__global__ __launch_bounds__(256) void k4b_fold(const _Float16* __restrict__ Wo16,
                                                const float* __restrict__ ctx,
                                                const float* __restrict__ sumexp,
                                                _Float16* __restrict__ M) {
  const int mq = blockIdx.x, b = blockIdx.y;
  const int t = threadIdx.x;
  const int h = t >> 6, l = t & 63;
  const int m0 = mq * 64;
  const float* cb = ctx + (size_t)(b * 4 + h) * 1024;
  const float* sb = sumexp + b * 128 + h * 32;
  half8 bf[2];
  #pragma unroll
  for (int n0 = 0; n0 < 2; ++n0) {
    int d = n0 * 16 + (l & 15);
    float s = SCALE_F / sb[d];
    const float* ce = cb + d * 32 + (l >> 4) * 8;
    half8 hb;
    #pragma unroll
    for (int j = 0; j < 8; ++j) hb[j] = (_Float16)(ce[j] * s);
    bf[n0] = hb;
  }
  const f32x4 fz = {0.f, 0.f, 0.f, 0.f};
  _Float16* Mb = M + (size_t)(b * 256) * 128;
  #pragma unroll
  for (int mf = 0; mf < 4; ++mf) {
    int row = m0 + mf * 16 + (l & 15);
    half8 af = *(const half8*)(Wo16 + (size_t)row * 128 + h * 32 + (l >> 4) * 8);
    #pragma unroll
    for (int n0 = 0; n0 < 2; ++n0) {
      f32x4 c = __builtin_amdgcn_mfma_f32_16x16x32_f16(af, bf[n0], fz, 0, 0, 0);
      #pragma unroll
      for (int rr = 0; rr < 4; ++rr) {
        int r = m0 + mf * 16 + (l >> 4) * 4 + rr;
        Mb[(size_t)r * 128 + h * 32 + n0 * 16 + (l & 15)] = (_Float16)c[rr];
      }
    }
  }
}

// ---------------- k5: out = rmsnorm(M @ qhat + b_out, g_out), f32 ----------
__global__ __launch_bounds__(256) void k5c_out(const _Float16* __restrict__ M,
                                               const _Float16* __restrict__ qhat,
                                               const float* __restrict__ b_out,
                                               const float* __restrict__ g_out,
                                               float* __restrict__ out) {
  const int pt = blockIdx.x, b = blockIdx.y;
  const int p0 = pt * 64;
  const int t = threadIdx.x;
  const int wid = t >> 6, l = t & 63;
  __shared__ __align__(16) char smem[81920];
  float* rp = (float*)smem;                   // [256][68]
  float* bo = (float*)(smem + 69632);
  float* g16o = (float*)(smem + 70656);
  float* psum = (float*)(smem + 71680);
  float* sinvp = (float*)(smem + 72704);
  const _Float16* Mb = M + (size_t)b * 256 * 128;
  const _Float16* Qb = qhat + ((size_t)b * 4096 + p0) * 128;
  #pragma unroll
  for (int i = 0; i < 16; ++i) {
    int ci = t + 256 * i;
    int r = ci >> 4, c = ci & 15;
    *(half8*)(smem + r * 256 + ((c ^ (r & 15)) << 4)) = *(const half8*)(Mb + (size_t)r * 128 + c * 8);
  }
  #pragma unroll
  for (int i = 0; i < 4; ++i) {
    int ci = t + 256 * i;
    int r = ci >> 4, c = ci & 15;
    *(half8*)(smem + 65536 + r * 256 + ((c ^ (r & 15)) << 4)) = *(const half8*)(Qb + (size_t)r * 128 + c * 8);
  }
  __syncthreads();
  const f32x4 fz = {0.f, 0.f, 0.f, 0.f};
  f32x4 acc[4][4];
  #pragma unroll
  for (int i = 0; i < 4; ++i)
    #pragma unroll
    for (int j = 0; j < 4; ++j) acc[i][j] = fz;
  #pragma unroll
  for (int kk = 0; kk < 4; ++kk) {
    half8 af[4], bf[4];
    int ck = kk * 4 + (l >> 4);
    #pragma unroll
    for (int mf = 0; mf < 4; ++mf) {
      int r = wid * 64 + mf * 16 + (l & 15);
      af[mf] = *(const half8*)(smem + r * 256 + ((ck ^ (r & 15)) << 4));
    }
    #pragma unroll
    for (int nf = 0; nf < 4; ++nf) {
      int r = nf * 16 + (l & 15);
      bf[nf] = *(const half8*)(smem + 65536 + r * 256 + ((ck ^ (r & 15)) << 4));
    }
    #pragma unroll
    for (int mf = 0; mf < 4; ++mf)
      #pragma unroll
      for (int nf = 0; nf < 4; ++nf)
        acc[mf][nf] = __builtin_amdgcn_mfma_f32_16x16x32_f16(af[mf], bf[nf], acc[mf][nf], 0, 0, 0);
  }
  __syncthreads();
  bo[t] = b_out[t];
  g16o[t] = g_out[t] * 16.0f;
  #pragma unroll
  for (int mf = 0; mf < 4; ++mf)
    #pragma unroll
    for (int nf = 0; nf < 4; ++nf)
      #pragma unroll
      for (int rr = 0; rr < 4; ++rr) {
        int r = wid * 64 + mf * 16 + (l >> 4) * 4 + rr;
        int px = nf * 16 + (l & 15);
        rp[r * 68 + px] = acc[mf][nf][rr];
      }
  __syncthreads();
  {
    int px = t & 63, q = t >> 6;
    float s = 0.f;
    #pragma unroll
    for (int i = 0; i < 64; ++i) {
      int r = q * 64 + i;
      float f = rp[r * 68 + px] + bo[r];
      s += f * f;
    }
    psum[px * 4 + q] = s;
  }
  __syncthreads();
  if (t < 64)
    sinvp[t] = rsqrtf(psum[t * 4] + psum[t * 4 + 1] + psum[t * 4 + 2] + psum[t * 4 + 3] + 1e-12f);
  __syncthreads();
  float* ob = out + (size_t)(b * 256) * 4096 + p0;
  #pragma unroll
  for (int i = 0; i < 16; ++i) {
    int idx4 = t + 256 * i;
    int r = idx4 >> 4, px4 = (idx4 & 15) * 4;
    f32x4 v;
    #pragma unroll
    for (int ii = 0; ii < 4; ++ii)
      v[ii] = (rp[r * 68 + px4 + ii] + bo[r]) * sinvp[px4 + ii] * g16o[r];
    *(f32x4*)(ob + (size_t)r * 4096 + px4) = v;
  }
}

extern "C" void kernel_launch(void* const* d_in, const int* in_sizes, int n_in,
                              void* d_out, int out_size, void* d_ws, size_t ws_size,
                              hipStream_t stream) {
  const float* x      = (const float*)d_in[0];
  const float* W_qkv  = (const float*)d_in[1];
  const float* W_out  = (const float*)d_in[2];
  const float* b_out  = (const float*)d_in[3];
  const float* g_norm = (const float*)d_in[4];
  const float* g_out  = (const float*)d_in[5];
  float* out = (float*)d_out;
  char* ws = (char*)d_ws;
  if (ws_size < 35659776) return;

  _Float16* W16   = (_Float16*)(ws);
  _Float16* Wo16  = (_Float16*)(ws + 196608);
  _Float16* qhat  = (_Float16*)(ws + 262144);
  float*    ctx   = (float*)(ws + 17039360);
  float*    sume  = (float*)(ws + 17301504);
  _Float16* M     = (_Float16*)(ws + 17309696);
  float*    ctxp  = (float*)(ws + 18358272);
  float*    sumep = (float*)(ws + 35135488);

  kW<<<16, 256, 0, stream>>>(W_qkv, W_out, g_norm, W16, Wo16);
  k2_mega<<<dim3(64, 16), 256, 0, stream>>>(W16, x, qhat, ctxp, sumep);
  k3_reduce<<<dim3(16, 16), 256, 0, stream>>>(ctxp, sumep, ctx, sume);
  k4b_fold<<<dim3(4, 16), 256, 0, stream>>>(Wo16, ctx, sume, M);
  k5c_out<<<dim3(64, 16), 256, 0, stream>>>(M, qhat, b_out, g_out, out);
}